// Round 19
// baseline (2599.855 us; speedup 1.0000x reference)
//
#include <hip/hip_runtime.h>
#include <math.h>

// Problem constants (fixed by reference file)
#define NB   512    // N = batch of user pairs
#define MM   254    // M uav nodes
#define SS   256    // S = M + 2 graph nodes per b
#define HH   128    // H hidden
#define RTOT 1278   // 2N + M rows in `outputs`
#define NBLK 256    // decode blocks; each handles b and b+256

#define C2   2.885390081777927f   // 2*log2(e): tanh arg pre-scale
#define C1   1.442695040888963f   // log2(e)

__device__ __forceinline__ float rcpf(float x)  { return __builtin_amdgcn_rcpf(x); }
__device__ __forceinline__ float exp2f_(float x){ return __builtin_amdgcn_exp2f(x); }
__device__ __forceinline__ float sigm2(float x) { return rcpf(1.0f + exp2f_(-C1 * x)); }
__device__ __forceinline__ float tanh2(float x) { return 1.0f - 2.0f * rcpf(1.0f + exp2f_(C2 * x)); }

// fused-logit 8-term slice: sum_i v[i] * rcp(1 + 2^(px*a[i]+py*b[i]+qc[i]))
__device__ __forceinline__ float dot8(float4 aA, float4 aB, float4 bA, float4 bB,
                                      float4 vA, float4 vB, float4 qA, float4 qB,
                                      float pxn, float pyn) {
  float acc = 0.f;
  acc = fmaf(vA.x, rcpf(1.0f + exp2f_(fmaf(pxn, aA.x, fmaf(pyn, bA.x, qA.x)))), acc);
  acc = fmaf(vA.y, rcpf(1.0f + exp2f_(fmaf(pxn, aA.y, fmaf(pyn, bA.y, qA.y)))), acc);
  acc = fmaf(vA.z, rcpf(1.0f + exp2f_(fmaf(pxn, aA.z, fmaf(pyn, bA.z, qA.z)))), acc);
  acc = fmaf(vA.w, rcpf(1.0f + exp2f_(fmaf(pxn, aA.w, fmaf(pyn, bA.w, qA.w)))), acc);
  acc = fmaf(vB.x, rcpf(1.0f + exp2f_(fmaf(pxn, aB.x, fmaf(pyn, bB.x, qB.x)))), acc);
  acc = fmaf(vB.y, rcpf(1.0f + exp2f_(fmaf(pxn, aB.y, fmaf(pyn, bB.y, qB.y)))), acc);
  acc = fmaf(vB.z, rcpf(1.0f + exp2f_(fmaf(pxn, aB.z, fmaf(pyn, bB.z, qB.z)))), acc);
  acc = fmaf(vB.w, rcpf(1.0f + exp2f_(fmaf(pxn, aB.w, fmaf(pyn, bB.w, qB.w)))), acc);
  return acc;
}

// pos is 2-D, so e = pos@Wemb+bemb is rank-2 in (px,py); therefore
//   EWi[r][j] = px*Ai[j] + py*Bi[j] + Ci[j]          (Ci includes lstm_b)
//   C2*W1e[r][h] = px*A1s[h] + py*B1s[h] + C1s[h]    (pre-scaled by C2)
// coef layout: Ai[512] Bi[512] Ci[512] A1s[128] B1s[128] C1s[128]
__global__ __launch_bounds__(512) void coef_k(
    const float* __restrict__ Wemb, const float* __restrict__ bemb,
    const float* __restrict__ Wi, const float* __restrict__ W1,
    const float* __restrict__ lb, float* __restrict__ coef)
{
  int j = threadIdx.x;  // 0..511
  float a = 0.f, b = 0.f, c = 0.f;
#pragma unroll 8
  for (int h = 0; h < HH; ++h) {
    float w = Wi[(size_t)h * 512 + j];
    a = fmaf(Wemb[h], w, a);
    b = fmaf(Wemb[HH + h], w, b);
    c = fmaf(bemb[h], w, c);
  }
  coef[j] = a; coef[512 + j] = b; coef[1024 + j] = c + lb[j];
  if (j < HH) {
    float a1 = 0.f, b1 = 0.f, c1 = 0.f;
#pragma unroll 8
    for (int h = 0; h < HH; ++h) {
      float w = W1[(size_t)h * HH + j];
      a1 = fmaf(Wemb[h], w, a1);
      b1 = fmaf(Wemb[HH + h], w, b1);
      c1 = fmaf(bemb[h], w, c1);
    }
    coef[1536 + j] = C2 * a1; coef[1664 + j] = C2 * b1; coef[1792 + j] = C2 * c1;
  }
}

// WhT[512][128] = Wh^T, W2T[128][128] = W2^T (per-thread-row float4 reads)
__global__ __launch_bounds__(128) void transpose_k(
    const float* __restrict__ Wh, const float* __restrict__ W2,
    float* __restrict__ WhT, float* __restrict__ W2T)
{
  int bidx = blockIdx.x;  // 0..639
  int k = threadIdx.x;    // 0..127
  if (bidx < 512) WhT[(size_t)bidx * 128 + k] = Wh[(size_t)k * 512 + bidx];
  else {
    int j = bidx - 512;
    W2T[(size_t)j * 128 + k] = W2[(size_t)k * 128 + j];
  }
}

// One block per TWO batch elements (b, b+256). 1024 threads, grid 256.
// 64-VGPR hard budget: no persistent per-thread arrays, and NO fully
// unrolled gather loops (full unroll of E's 8-gather c-loop was the spill
// source in r16-r18: 8 concurrent posU/actS gathers blow the live set).
// E: transient slice constants (8x float4) + c-loop at unroll 2.
__global__ __attribute__((amdgpu_waves_per_eu(4, 4)))
__launch_bounds__(1024) void decode_k(
    const float* __restrict__ outputs, const float* __restrict__ WhT,
    const float* __restrict__ Wh, const float* __restrict__ W2T,
    const float* __restrict__ av, const float* __restrict__ coef,
    float* __restrict__ maxd_out)
{
  const int t = threadIdx.x;   // 0..1023
  const int bid = blockIdx.x;

  __shared__ float WhL[64][512];            // 128 KB: Wh rows 64..127
  __shared__ float posU[2 * MM];            // uav node positions
  __shared__ float dstS[2][2];              // per-g dst node position
  __shared__ float curP[2][2];              // per-g current node position
  __shared__ __align__(16) float hS[2][HH];
  __shared__ __align__(16) float qC[2][HH]; // C2*q + C1s
  __shared__ float C1sS[HH];
  __shared__ __align__(16) float A1sS[HH], B1sS[HH], vS2[HH];
  __shared__ __align__(16) float AiS[512], BiS[512], CiS[512];
  __shared__ float pS[2][2][512];           // gates partials [g][gh][j]
  __shared__ float lgS[2][SS];              // final logits (shifted by -sumv)
  __shared__ int   actS[2][254];
  __shared__ int   cntS[2];

  // Bank-conflict-free gates mapping: within each 32-lane group gh is
  // uniform and gj covers 32 consecutive values (banks 0..31 distinct).
  const int gh  = (t >> 5) & 1;            // gates k-half (0/1)
  const int gj  = ((t >> 6) << 5) | (t & 31);  // gates column, 0..511
  const int cg  = t >> 9;        // q batch slot
  const int cj  = (t >> 2) & 127;// q column
  const int ckq = t & 3;         // q k-quarter

  // E mapping: per g, 8 waves; lane = eul*16 + esl; u = ewv*4 + eul + 32*c.
  const int eg  = t >> 9;              // E batch slot
  const int tg  = t & 511;
  const int ewv = tg >> 6;             // wave within g: 0..7
  const int eul = (tg >> 4) & 3;       // u_local: 0..3
  const int esl = tg & 15;             // h-slice: 0..15 (8 h each)

  // ---- init ----
  for (int i = t; i < 64 * 512; i += 1024) ((float*)WhL)[i] = Wh[64 * 512 + i];
  for (int i = t; i < 2 * MM; i += 1024)   posU[i] = outputs[4 * NB + i];
  if (t < HH) {
    C1sS[t] = coef[1792 + t];
    A1sS[t] = coef[1536 + t];
    B1sS[t] = coef[1664 + t];
    vS2[t]  = -2.0f * av[t];
  }
  if (t < 512) { AiS[t] = coef[t]; BiS[t] = coef[512 + t]; CiS[t] = coef[1024 + t]; }
  if (t < 256) { int gg = t >> 7, j = t & 127; hS[gg][j] = 0.f; }
  if (t < 254) actS[0][t] = t + 1;
  else if (t >= 512 && t < 766) actS[1][t - 512] = t - 511;
  if (t == 0) {
    cntS[0] = 254;
    dstS[0][0] = outputs[2 * (NB + bid)]; dstS[0][1] = outputs[2 * (NB + bid) + 1];
    curP[0][0] = outputs[2 * bid];        curP[0][1] = outputs[2 * bid + 1];
  }
  if (t == 512) {
    cntS[1] = 254;
    dstS[1][0] = outputs[2 * (NB + bid + NBLK)];
    dstS[1][1] = outputs[2 * (NB + bid + NBLK) + 1];
    curP[1][0] = outputs[2 * (bid + NBLK)];
    curP[1][1] = outputs[2 * (bid + NBLK) + 1];
  }
  __syncthreads();

  float px = 0.f, py = 0.f, md = 0.f;   // live in t==0 (g0) and t==512 (g1)
  if (t == 0)   { px = curP[0][0]; py = curP[0][1]; }
  if (t == 512) { px = curP[1][0]; py = curP[1][1]; }

  float creg = 0.f;                     // LSTM c-state, owned by t<256

  for (int k = 0; k < SS; ++k) {
    // ---- Phase A: gates partials. k in gh*32+[0,32) from WhT (two 4-float4
    // bursts, latency hidden under the LDS half), k in 64+gh*32+[0,32) from
    // WhL (conflict-free scalar). Both g per thread.
    {
      const float4* wg4 = (const float4*)(WhT + (size_t)gj * 128 + gh * 32);
      const float*  wl  = &WhL[gh * 32][gj];
      const float4* hb0g = (const float4*)(&hS[0][gh * 32]);
      const float4* hb1g = (const float4*)(&hS[1][gh * 32]);
      const float4* hb0l = (const float4*)(&hS[0][64 + gh * 32]);
      const float4* hb1l = (const float4*)(&hS[1][64 + gh * 32]);
      float a0G = 0.f, a1G = 0.f, a0L = 0.f, a1L = 0.f;
      float4 wb[4];
      // burst 1 (k offsets 0..15)
#pragma unroll
      for (int i = 0; i < 4; ++i) wb[i] = wg4[i];
      // LDS half part 1 while burst 1 is in flight
#pragma unroll
      for (int i = 0; i < 4; ++i) {
        float4 h0 = hb0l[i], h1 = hb1l[i];
        float wa = wl[(size_t)(4 * i) * 512];
        float wbv = wl[(size_t)(4 * i + 1) * 512];
        float wc = wl[(size_t)(4 * i + 2) * 512];
        float wd = wl[(size_t)(4 * i + 3) * 512];
        a0L = fmaf(h0.x, wa, a0L); a0L = fmaf(h0.y, wbv, a0L);
        a0L = fmaf(h0.z, wc, a0L); a0L = fmaf(h0.w, wd, a0L);
        a1L = fmaf(h1.x, wa, a1L); a1L = fmaf(h1.y, wbv, a1L);
        a1L = fmaf(h1.z, wc, a1L); a1L = fmaf(h1.w, wd, a1L);
      }
      // consume burst 1 (h indices gh*32 + 0..15)
#pragma unroll
      for (int i = 0; i < 4; ++i) {
        float4 h0 = hb0g[i], h1 = hb1g[i], w = wb[i];
        a0G = fmaf(h0.x, w.x, a0G); a0G = fmaf(h0.y, w.y, a0G);
        a0G = fmaf(h0.z, w.z, a0G); a0G = fmaf(h0.w, w.w, a0G);
        a1G = fmaf(h1.x, w.x, a1G); a1G = fmaf(h1.y, w.y, a1G);
        a1G = fmaf(h1.z, w.z, a1G); a1G = fmaf(h1.w, w.w, a1G);
      }
      // burst 2 (k offsets 16..31)
#pragma unroll
      for (int i = 0; i < 4; ++i) wb[i] = wg4[4 + i];
      // LDS half part 2 while burst 2 is in flight
#pragma unroll
      for (int i = 4; i < 8; ++i) {
        float4 h0 = hb0l[i], h1 = hb1l[i];
        float wa = wl[(size_t)(4 * i) * 512];
        float wbv = wl[(size_t)(4 * i + 1) * 512];
        float wc = wl[(size_t)(4 * i + 2) * 512];
        float wd = wl[(size_t)(4 * i + 3) * 512];
        a0L = fmaf(h0.x, wa, a0L); a0L = fmaf(h0.y, wbv, a0L);
        a0L = fmaf(h0.z, wc, a0L); a0L = fmaf(h0.w, wd, a0L);
        a1L = fmaf(h1.x, wa, a1L); a1L = fmaf(h1.y, wbv, a1L);
        a1L = fmaf(h1.z, wc, a1L); a1L = fmaf(h1.w, wd, a1L);
      }
      // consume burst 2 (h indices gh*32 + 16..31)
#pragma unroll
      for (int i = 0; i < 4; ++i) {
        float4 h0 = hb0g[4 + i], h1 = hb1g[4 + i], w = wb[i];
        a0G = fmaf(h0.x, w.x, a0G); a0G = fmaf(h0.y, w.y, a0G);
        a0G = fmaf(h0.z, w.z, a0G); a0G = fmaf(h0.w, w.w, a0G);
        a1G = fmaf(h1.x, w.x, a1G); a1G = fmaf(h1.y, w.y, a1G);
        a1G = fmaf(h1.z, w.z, a1G); a1G = fmaf(h1.w, w.w, a1G);
      }
      pS[0][gh][gj] = a0G + a0L;
      pS[1][gh][gj] = a1G + a1L;
    }
    __syncthreads();  // B1

    // ---- Phase B: LSTM cell (t<256; order i,f,g,o); EWi from LDS coef
    if (t < 256) {
      int g = t >> 7, jj = t & 127;
      float pxc = curP[g][0], pyc = curP[g][1];
      float ei = fmaf(pxc, AiS[jj],       fmaf(pyc, BiS[jj],       CiS[jj]))       + (pS[g][0][jj]       + pS[g][1][jj]);
      float ef = fmaf(pxc, AiS[128 + jj], fmaf(pyc, BiS[128 + jj], CiS[128 + jj])) + (pS[g][0][128 + jj] + pS[g][1][128 + jj]);
      float eg2 = fmaf(pxc, AiS[256 + jj], fmaf(pyc, BiS[256 + jj], CiS[256 + jj])) + (pS[g][0][256 + jj] + pS[g][1][256 + jj]);
      float eo = fmaf(pxc, AiS[384 + jj], fmaf(pyc, BiS[384 + jj], CiS[384 + jj])) + (pS[g][0][384 + jj] + pS[g][1][384 + jj]);
      float iv = sigm2(ei), fv = sigm2(ef), gv = tanh2(eg2), ov = sigm2(eo);
      float cn = fv * creg + iv * gv;
      creg = cn;
      hS[g][jj] = ov * tanh2(cn);
    }
    __syncthreads();  // B2

    // ---- Phase C: q[g][j], quad k-split + shfl reduce; fold C1s in
    {
      const float4* w4 = (const float4*)(W2T + (size_t)cj * 128 + ckq * 32);
      const float4* h4 = (const float4*)(&hS[cg][ckq * 32]);
      float p0 = 0.f, p1 = 0.f;
#pragma unroll
      for (int i = 0; i < 8; ++i) {
        float4 w = w4[i], h = h4[i];
        p0 = fmaf(h.x, w.x, p0); p1 = fmaf(h.y, w.y, p1);
        p0 = fmaf(h.z, w.z, p0); p1 = fmaf(h.w, w.w, p1);
      }
      float p = p0 + p1;
      p += __shfl_xor(p, 1);
      p += __shfl_xor(p, 2);
      if (ckq == 0) qC[cg][cj] = fmaf(C2, p, C1sS[cj]);
    }
    __syncthreads();  // B3

    // ---- Phase E: logits (shifted by -sumv: argmax-invariant).
    // TRANSIENT slice constants from LDS (8 b128); 8 u x 8 h per thread;
    // 16-lane shfl-xor reduce; esl==0 lanes write lgS.
    // unroll 2: full unroll of the 8-gather loop was the r16-r18 spill.
    {
      int cnt = cntS[eg];
      int cntEff = cnt + (k > 0 ? 1 : 0);
      const float4* a4 = (const float4*)(&A1sS[esl * 8]);
      const float4* b4 = (const float4*)(&B1sS[esl * 8]);
      const float4* v4 = (const float4*)(&vS2[esl * 8]);
      const float4* q4 = (const float4*)(&qC[eg][esl * 8]);
      float4 aA = a4[0], aB = a4[1];
      float4 bA = b4[0], bB = b4[1];
      float4 vA = v4[0], vB = v4[1];
      float4 qA = q4[0], qB = q4[1];
#pragma unroll 2
      for (int c = 0; c < 8; ++c) {
        int u = ewv * 4 + eul + 32 * c;
        if (u < cntEff) {
          int s = (u == cnt) ? 255 : actS[eg][u];
          float pxn, pyn;
          if (s == 255) { pxn = dstS[eg][0]; pyn = dstS[eg][1]; }
          else          { pxn = posU[2 * (s - 1)]; pyn = posU[2 * (s - 1) + 1]; }
          float acc = dot8(aA, aB, bA, bB, vA, vB, qA, qB, pxn, pyn);
          acc += __shfl_xor(acc, 1);
          acc += __shfl_xor(acc, 2);
          acc += __shfl_xor(acc, 4);
          acc += __shfl_xor(acc, 8);
          if (esl == 0) lgS[eg][u] = acc;
        }
      }
    }
    __syncthreads();  // B4

    // ---- Phase F: argmax + state update (wave 0 -> g0, wave 8 -> g1)
    if ((t < 64) || (t >= 512 && t < 576)) {
      int g = t >> 9;
      int lane = t & 63;
      int cnt = cntS[g];
      int cntEff = cnt + (k > 0 ? 1 : 0);
      float val = -INFINITY;
      unsigned key = 0xFFFFFFFFu;
#pragma unroll 2
      for (int c = 0; c < 4; ++c) {
        int u = lane + 64 * c;
        if (u < cntEff) {
          float v2 = lgS[g][u];
          int s = (u == cnt) ? 255 : actS[g][u];
          unsigned k2 = ((unsigned)s << 16) | (unsigned)u;
          if (v2 > val || (v2 == val && k2 < key)) { val = v2; key = k2; }
        }
      }
#pragma unroll
      for (int off = 1; off < 64; off <<= 1) {
        float v2 = __shfl_xor(val, off);
        unsigned k2 = __shfl_xor(key, off);
        if (v2 > val || (v2 == val && k2 < key)) { val = v2; key = k2; }
      }
      if (lane == 0) {
        int s   = (int)(key >> 16);
        int pos = (int)(key & 0xFFFFu);
        float nx, ny;
        if (s == 255) { nx = dstS[g][0]; ny = dstS[g][1]; }
        else          { nx = posU[2 * (s - 1)]; ny = posU[2 * (s - 1) + 1]; }
        float dx = nx - px, dy = ny - py;
        float d = sqrtf(dx * dx + dy * dy + 1e-12f);
        if (d > md) md = d;
        px = nx; py = ny;
        curP[g][0] = nx; curP[g][1] = ny;
        if (s != 255) { actS[g][pos] = actS[g][cnt - 1]; cntS[g] = cnt - 1; }
      }
    }
    __syncthreads();  // B5
  }

  if (t == 0)   maxd_out[bid] = md;
  if (t == 512) maxd_out[bid + NBLK] = md;
}

__global__ __launch_bounds__(512) void reduce_k(const float* __restrict__ maxd,
                                               float* __restrict__ out)
{
  __shared__ float s[512];
  int t = threadIdx.x;
  s[t] = maxd[t];
  __syncthreads();
  for (int off = 256; off > 0; off >>= 1) {
    if (t < off) s[t] += s[t + off];
    __syncthreads();
  }
  if (t == 0) out[0] = s[0] * (1.0f / 512.0f);
}

extern "C" void kernel_launch(void* const* d_in, const int* in_sizes, int n_in,
                              void* d_out, int out_size, void* d_ws, size_t ws_size,
                              hipStream_t stream) {
  const float* outputs = (const float*)d_in[0];
  const float* Wemb    = (const float*)d_in[1];
  const float* bemb    = (const float*)d_in[2];
  const float* Wi      = (const float*)d_in[3];
  const float* Wh      = (const float*)d_in[4];
  const float* lb      = (const float*)d_in[5];
  const float* W1      = (const float*)d_in[6];
  const float* W2      = (const float*)d_in[7];
  const float* av      = (const float*)d_in[8];
  // d_in[9] = N (known constant 512)

  float* ws   = (float*)d_ws;
  float* coef = ws;                        // 1920 floats
  float* WhT  = coef + 2048;               // 512*128
  float* W2T  = WhT + (size_t)512 * 128;   // 128*128
  float* maxd = W2T + (size_t)128 * 128;   // 512

  hipLaunchKernelGGL(coef_k, dim3(1), dim3(512), 0, stream,
                     Wemb, bemb, Wi, W1, lb, coef);
  hipLaunchKernelGGL(transpose_k, dim3(640), dim3(128), 0, stream, Wh, W2, WhT, W2T);
  hipLaunchKernelGGL(decode_k, dim3(NBLK), dim3(1024), 0, stream,
                     outputs, WhT, Wh, W2T, av, coef, maxd);
  hipLaunchKernelGGL(reduce_k, dim3(1), dim3(512), 0, stream, maxd, (float*)d_out);
}

// Round 21
// 2122.290 us; speedup vs baseline: 1.2250x; 1.2250x over previous
//
#include <hip/hip_runtime.h>
#include <math.h>

// Problem constants (fixed by reference file)
#define NB   512    // N = batch of user pairs
#define MM   254    // M uav nodes
#define SS   256    // S = M + 2 graph nodes per b
#define HH   128    // H hidden
#define RTOT 1278   // 2N + M rows in `outputs`
#define NBLK 256    // decode blocks; each handles b and b+256

#define C2   2.885390081777927f   // 2*log2(e): tanh arg pre-scale
#define C1   1.442695040888963f   // log2(e)

__device__ __forceinline__ float rcpf(float x)  { return __builtin_amdgcn_rcpf(x); }
__device__ __forceinline__ float exp2f_(float x){ return __builtin_amdgcn_exp2f(x); }
__device__ __forceinline__ float sigm2(float x) { return rcpf(1.0f + exp2f_(-C1 * x)); }
__device__ __forceinline__ float tanh2(float x) { return 1.0f - 2.0f * rcpf(1.0f + exp2f_(C2 * x)); }

// pos is 2-D, so e = pos@Wemb+bemb is rank-2 in (px,py); therefore
//   EWi[r][j] = px*Ai[j] + py*Bi[j] + Ci[j]          (Ci includes lstm_b)
//   C2*W1e[r][h] = px*A1s[h] + py*B1s[h] + C1s[h]    (pre-scaled by C2)
// coef layout: Ai[512] Bi[512] Ci[512] A1s[128] B1s[128] C1s[128]
__global__ __launch_bounds__(512) void coef_k(
    const float* __restrict__ Wemb, const float* __restrict__ bemb,
    const float* __restrict__ Wi, const float* __restrict__ W1,
    const float* __restrict__ lb, float* __restrict__ coef)
{
  int j = threadIdx.x;  // 0..511
  float a = 0.f, b = 0.f, c = 0.f;
#pragma unroll 8
  for (int h = 0; h < HH; ++h) {
    float w = Wi[(size_t)h * 512 + j];
    a = fmaf(Wemb[h], w, a);
    b = fmaf(Wemb[HH + h], w, b);
    c = fmaf(bemb[h], w, c);
  }
  coef[j] = a; coef[512 + j] = b; coef[1024 + j] = c + lb[j];
  if (j < HH) {
    float a1 = 0.f, b1 = 0.f, c1 = 0.f;
#pragma unroll 8
    for (int h = 0; h < HH; ++h) {
      float w = W1[(size_t)h * HH + j];
      a1 = fmaf(Wemb[h], w, a1);
      b1 = fmaf(Wemb[HH + h], w, b1);
      c1 = fmaf(bemb[h], w, c1);
    }
    coef[1536 + j] = C2 * a1; coef[1664 + j] = C2 * b1; coef[1792 + j] = C2 * c1;
  }
}

// WhT[512][128] = Wh^T, W2T[128][128] = W2^T (per-thread-row float4 reads)
__global__ __launch_bounds__(128) void transpose_k(
    const float* __restrict__ Wh, const float* __restrict__ W2,
    float* __restrict__ WhT, float* __restrict__ W2T)
{
  int bidx = blockIdx.x;  // 0..639
  int k = threadIdx.x;    // 0..127
  if (bidx < 512) WhT[(size_t)bidx * 128 + k] = Wh[(size_t)k * 512 + bidx];
  else {
    int j = bidx - 512;
    W2T[(size_t)j * 128 + k] = W2[(size_t)k * 128 + j];
  }
}

// One block per TWO batch elements (b, b+256). 1024 threads, grid 256.
// r15 base (proven no-spill) + E at 4-way h-quarter x 2 nodes/thread:
// constant streams read once per iteration and shared by both nodes ->
// E's LDS traffic halves (64 -> 32 b128/thread) at r15 register pressure.
// (lsS dropped vs r20 draft: F recomputes s from actS; LDS was 8 B over.)
__global__ __attribute__((amdgpu_waves_per_eu(4, 4)))
__launch_bounds__(1024) void decode_k(
    const float* __restrict__ outputs, const float* __restrict__ WhT,
    const float* __restrict__ Wh, const float* __restrict__ W2T,
    const float* __restrict__ av, const float* __restrict__ coef,
    float* __restrict__ maxd_out)
{
  const int t = threadIdx.x;   // 0..1023
  const int bid = blockIdx.x;

  __shared__ float WhL[64][512];            // 128 KB: Wh rows 64..127
  __shared__ float posU[2 * MM];            // uav node positions
  __shared__ float dstS[2][2];              // per-g dst node position
  __shared__ float curP[2][2];              // per-g current node position
  __shared__ __align__(16) float hS[2][HH];
  __shared__ __align__(16) float qC[2][HH]; // C2*q + C1s
  __shared__ float C1sS[HH];
  __shared__ __align__(16) float A1sS[HH], B1sS[HH], vS2[HH];
  __shared__ __align__(16) float AiS[512], BiS[512], CiS[512];
  __shared__ float pS[2][2][512];           // gates partials [g][gh][j]
  __shared__ float lp[2][4][SS];            // logit partials [g][hquarter][u]
  __shared__ int   actS[2][254];
  __shared__ int   cntS[2];

  // Bank-conflict-free gates mapping: within each 32-lane group gh is
  // uniform and gj covers 32 consecutive values (banks 0..31 distinct).
  const int gh  = (t >> 5) & 1;            // gates k-half (0/1)
  const int gj  = ((t >> 6) << 5) | (t & 31);  // gates column, 0..511
  const int cg  = t >> 9;        // q batch slot
  const int cj  = (t >> 2) & 127;// q column
  const int ckq = t & 3;         // q k-quarter
  const int lg  = t >> 9;        // logits batch slot
  const int lhq = (t >> 7) & 3;  // logits h-quarter (32 h)
  const int lu  = t & 127;       // logits base node slot (u, u+128)

  // ---- init ----
  for (int i = t; i < 64 * 512; i += 1024) ((float*)WhL)[i] = Wh[64 * 512 + i];
  for (int i = t; i < 2 * MM; i += 1024)   posU[i] = outputs[4 * NB + i];
  if (t < HH) {
    C1sS[t] = coef[1792 + t];
    A1sS[t] = coef[1536 + t];
    B1sS[t] = coef[1664 + t];
    vS2[t]  = -2.0f * av[t];
  }
  if (t < 512) { AiS[t] = coef[t]; BiS[t] = coef[512 + t]; CiS[t] = coef[1024 + t]; }
  if (t < 256) { int gg = t >> 7, j = t & 127; hS[gg][j] = 0.f; }
  if (t < 254) actS[0][t] = t + 1;
  else if (t >= 512 && t < 766) actS[1][t - 512] = t - 511;
  if (t == 0) {
    cntS[0] = 254;
    dstS[0][0] = outputs[2 * (NB + bid)]; dstS[0][1] = outputs[2 * (NB + bid) + 1];
    curP[0][0] = outputs[2 * bid];        curP[0][1] = outputs[2 * bid + 1];
  }
  if (t == 512) {
    cntS[1] = 254;
    dstS[1][0] = outputs[2 * (NB + bid + NBLK)];
    dstS[1][1] = outputs[2 * (NB + bid + NBLK) + 1];
    curP[1][0] = outputs[2 * (bid + NBLK)];
    curP[1][1] = outputs[2 * (bid + NBLK) + 1];
  }
  __syncthreads();

  float px = 0.f, py = 0.f, md = 0.f;   // live in t==0 (g0) and t==512 (g1)
  if (t == 0)   { px = curP[0][0]; py = curP[0][1]; }
  if (t == 512) { px = curP[1][0]; py = curP[1][1]; }

  float creg = 0.f;                     // LSTM c-state, owned by t<256

  for (int k = 0; k < SS; ++k) {
    // ---- Phase A: gates partials. k in gh*32+[0,32) from WhT (two 4-float4
    // bursts, latency hidden under the LDS half), k in 64+gh*32+[0,32) from
    // WhL (conflict-free scalar). Both g per thread.
    {
      const float4* wg4 = (const float4*)(WhT + (size_t)gj * 128 + gh * 32);
      const float*  wl  = &WhL[gh * 32][gj];
      const float4* hb0g = (const float4*)(&hS[0][gh * 32]);
      const float4* hb1g = (const float4*)(&hS[1][gh * 32]);
      const float4* hb0l = (const float4*)(&hS[0][64 + gh * 32]);
      const float4* hb1l = (const float4*)(&hS[1][64 + gh * 32]);
      float a0G = 0.f, a1G = 0.f, a0L = 0.f, a1L = 0.f;
      float4 wb[4];
      // burst 1 (k offsets 0..15)
#pragma unroll
      for (int i = 0; i < 4; ++i) wb[i] = wg4[i];
      // LDS half part 1 while burst 1 is in flight
#pragma unroll
      for (int i = 0; i < 4; ++i) {
        float4 h0 = hb0l[i], h1 = hb1l[i];
        float wa = wl[(size_t)(4 * i) * 512];
        float wbv = wl[(size_t)(4 * i + 1) * 512];
        float wc = wl[(size_t)(4 * i + 2) * 512];
        float wd = wl[(size_t)(4 * i + 3) * 512];
        a0L = fmaf(h0.x, wa, a0L); a0L = fmaf(h0.y, wbv, a0L);
        a0L = fmaf(h0.z, wc, a0L); a0L = fmaf(h0.w, wd, a0L);
        a1L = fmaf(h1.x, wa, a1L); a1L = fmaf(h1.y, wbv, a1L);
        a1L = fmaf(h1.z, wc, a1L); a1L = fmaf(h1.w, wd, a1L);
      }
      // consume burst 1 (h indices gh*32 + 0..15)
#pragma unroll
      for (int i = 0; i < 4; ++i) {
        float4 h0 = hb0g[i], h1 = hb1g[i], w = wb[i];
        a0G = fmaf(h0.x, w.x, a0G); a0G = fmaf(h0.y, w.y, a0G);
        a0G = fmaf(h0.z, w.z, a0G); a0G = fmaf(h0.w, w.w, a0G);
        a1G = fmaf(h1.x, w.x, a1G); a1G = fmaf(h1.y, w.y, a1G);
        a1G = fmaf(h1.z, w.z, a1G); a1G = fmaf(h1.w, w.w, a1G);
      }
      // burst 2 (k offsets 16..31)
#pragma unroll
      for (int i = 0; i < 4; ++i) wb[i] = wg4[4 + i];
      // LDS half part 2 while burst 2 is in flight
#pragma unroll
      for (int i = 4; i < 8; ++i) {
        float4 h0 = hb0l[i], h1 = hb1l[i];
        float wa = wl[(size_t)(4 * i) * 512];
        float wbv = wl[(size_t)(4 * i + 1) * 512];
        float wc = wl[(size_t)(4 * i + 2) * 512];
        float wd = wl[(size_t)(4 * i + 3) * 512];
        a0L = fmaf(h0.x, wa, a0L); a0L = fmaf(h0.y, wbv, a0L);
        a0L = fmaf(h0.z, wc, a0L); a0L = fmaf(h0.w, wd, a0L);
        a1L = fmaf(h1.x, wa, a1L); a1L = fmaf(h1.y, wbv, a1L);
        a1L = fmaf(h1.z, wc, a1L); a1L = fmaf(h1.w, wd, a1L);
      }
      // consume burst 2 (h indices gh*32 + 16..31)
#pragma unroll
      for (int i = 0; i < 4; ++i) {
        float4 h0 = hb0g[4 + i], h1 = hb1g[4 + i], w = wb[i];
        a0G = fmaf(h0.x, w.x, a0G); a0G = fmaf(h0.y, w.y, a0G);
        a0G = fmaf(h0.z, w.z, a0G); a0G = fmaf(h0.w, w.w, a0G);
        a1G = fmaf(h1.x, w.x, a1G); a1G = fmaf(h1.y, w.y, a1G);
        a1G = fmaf(h1.z, w.z, a1G); a1G = fmaf(h1.w, w.w, a1G);
      }
      pS[0][gh][gj] = a0G + a0L;
      pS[1][gh][gj] = a1G + a1L;
    }
    __syncthreads();  // B1

    // ---- Phase B: LSTM cell (t<256; order i,f,g,o); EWi from LDS coef
    if (t < 256) {
      int g = t >> 7, jj = t & 127;
      float pxc = curP[g][0], pyc = curP[g][1];
      float ei = fmaf(pxc, AiS[jj],       fmaf(pyc, BiS[jj],       CiS[jj]))       + (pS[g][0][jj]       + pS[g][1][jj]);
      float ef = fmaf(pxc, AiS[128 + jj], fmaf(pyc, BiS[128 + jj], CiS[128 + jj])) + (pS[g][0][128 + jj] + pS[g][1][128 + jj]);
      float eg2 = fmaf(pxc, AiS[256 + jj], fmaf(pyc, BiS[256 + jj], CiS[256 + jj])) + (pS[g][0][256 + jj] + pS[g][1][256 + jj]);
      float eo = fmaf(pxc, AiS[384 + jj], fmaf(pyc, BiS[384 + jj], CiS[384 + jj])) + (pS[g][0][384 + jj] + pS[g][1][384 + jj]);
      float iv = sigm2(ei), fv = sigm2(ef), gv = tanh2(eg2), ov = sigm2(eo);
      float cn = fv * creg + iv * gv;
      creg = cn;
      hS[g][jj] = ov * tanh2(cn);
    }
    __syncthreads();  // B2

    // ---- Phase C: q[g][j], quad k-split + shfl reduce; fold C1s in
    {
      const float4* w4 = (const float4*)(W2T + (size_t)cj * 128 + ckq * 32);
      const float4* h4 = (const float4*)(&hS[cg][ckq * 32]);
      float p0 = 0.f, p1 = 0.f;
#pragma unroll
      for (int i = 0; i < 8; ++i) {
        float4 w = w4[i], h = h4[i];
        p0 = fmaf(h.x, w.x, p0); p1 = fmaf(h.y, w.y, p1);
        p0 = fmaf(h.z, w.z, p0); p1 = fmaf(h.w, w.w, p1);
      }
      float p = p0 + p1;
      p += __shfl_xor(p, 1);
      p += __shfl_xor(p, 2);
      if (ckq == 0) qC[cg][cj] = fmaf(C2, p, C1sS[cj]);
    }
    __syncthreads();  // B3

    // ---- Phase E: logits; 4-way h-quarter, 2 nodes/thread. Constant
    // streams (a,b,qc,v) read once per iteration, shared by both nodes.
    // Gathers hoisted out of the i-loop. arg = px*A1s + py*B1s + qC.
    {
      int cnt = cntS[lg];
      int cntEff = cnt + (k > 0 ? 1 : 0);   // dst node re-enters for k>0
      int u0 = lu, u1 = lu + 128;
      bool e0 = u0 < cntEff, e1 = u1 < cntEff;
      float px0 = 0.f, py0 = 0.f, px1 = 0.f, py1 = 0.f;
      if (e0) {
        int s0 = (u0 == cnt) ? 255 : actS[lg][u0];
        if (s0 == 255) { px0 = dstS[lg][0]; py0 = dstS[lg][1]; }
        else           { px0 = posU[2 * (s0 - 1)]; py0 = posU[2 * (s0 - 1) + 1]; }
      }
      if (e1) {
        int s1 = (u1 == cnt) ? 255 : actS[lg][u1];
        if (s1 == 255) { px1 = dstS[lg][0]; py1 = dstS[lg][1]; }
        else           { px1 = posU[2 * (s1 - 1)]; py1 = posU[2 * (s1 - 1) + 1]; }
      }
      const float4* a14 = (const float4*)(&A1sS[lhq * 32]);
      const float4* b14 = (const float4*)(&B1sS[lhq * 32]);
      const float4* qc4 = (const float4*)(&qC[lg][lhq * 32]);
      const float4* vv4 = (const float4*)(&vS2[lhq * 32]);
      float c00 = 0.f, c01 = 0.f, c10 = 0.f, c11 = 0.f;
#pragma unroll 4
      for (int i = 0; i < 8; ++i) {
        float4 a = a14[i], b = b14[i], qc = qc4[i], v = vv4[i];
        if (e0) {
          c00 = fmaf(v.x, rcpf(1.0f + exp2f_(fmaf(px0, a.x, fmaf(py0, b.x, qc.x)))), c00);
          c01 = fmaf(v.y, rcpf(1.0f + exp2f_(fmaf(px0, a.y, fmaf(py0, b.y, qc.y)))), c01);
          c00 = fmaf(v.z, rcpf(1.0f + exp2f_(fmaf(px0, a.z, fmaf(py0, b.z, qc.z)))), c00);
          c01 = fmaf(v.w, rcpf(1.0f + exp2f_(fmaf(px0, a.w, fmaf(py0, b.w, qc.w)))), c01);
        }
        if (e1) {
          c10 = fmaf(v.x, rcpf(1.0f + exp2f_(fmaf(px1, a.x, fmaf(py1, b.x, qc.x)))), c10);
          c11 = fmaf(v.y, rcpf(1.0f + exp2f_(fmaf(px1, a.y, fmaf(py1, b.y, qc.y)))), c11);
          c10 = fmaf(v.z, rcpf(1.0f + exp2f_(fmaf(px1, a.z, fmaf(py1, b.z, qc.z)))), c10);
          c11 = fmaf(v.w, rcpf(1.0f + exp2f_(fmaf(px1, a.w, fmaf(py1, b.w, qc.w)))), c11);
        }
      }
      if (e0) lp[lg][lhq][u0] = c00 + c01;
      if (e1) lp[lg][lhq][u1] = c10 + c11;
    }
    __syncthreads();  // B4

    // ---- Phase F: argmax + state update (wave 0 -> g0, wave 8 -> g1)
    if ((t < 64) || (t >= 512 && t < 576)) {
      int g = t >> 9;
      int lane = t & 63;
      int cnt = cntS[g];
      int cntEff = cnt + (k > 0 ? 1 : 0);
      float val = -INFINITY;
      unsigned key = 0xFFFFFFFFu;
#pragma unroll 2
      for (int c = 0; c < 4; ++c) {
        int u = lane + 64 * c;
        if (u < cntEff) {
          float v2 = (lp[g][0][u] + lp[g][1][u]) + (lp[g][2][u] + lp[g][3][u]);
          int s = (u == cnt) ? 255 : actS[g][u];
          unsigned k2 = ((unsigned)s << 16) | (unsigned)u;
          if (v2 > val || (v2 == val && k2 < key)) { val = v2; key = k2; }
        }
      }
#pragma unroll
      for (int off = 1; off < 64; off <<= 1) {
        float v2 = __shfl_xor(val, off);
        unsigned k2 = __shfl_xor(key, off);
        if (v2 > val || (v2 == val && k2 < key)) { val = v2; key = k2; }
      }
      if (lane == 0) {
        int s   = (int)(key >> 16);
        int pos = (int)(key & 0xFFFFu);
        float nx, ny;
        if (s == 255) { nx = dstS[g][0]; ny = dstS[g][1]; }
        else          { nx = posU[2 * (s - 1)]; ny = posU[2 * (s - 1) + 1]; }
        float dx = nx - px, dy = ny - py;
        float d = sqrtf(dx * dx + dy * dy + 1e-12f);
        if (d > md) md = d;
        px = nx; py = ny;
        curP[g][0] = nx; curP[g][1] = ny;
        if (s != 255) { actS[g][pos] = actS[g][cnt - 1]; cntS[g] = cnt - 1; }
      }
    }
    __syncthreads();  // B5
  }

  if (t == 0)   maxd_out[bid] = md;
  if (t == 512) maxd_out[bid + NBLK] = md;
}

__global__ __launch_bounds__(512) void reduce_k(const float* __restrict__ maxd,
                                               float* __restrict__ out)
{
  __shared__ float s[512];
  int t = threadIdx.x;
  s[t] = maxd[t];
  __syncthreads();
  for (int off = 256; off > 0; off >>= 1) {
    if (t < off) s[t] += s[t + off];
    __syncthreads();
  }
  if (t == 0) out[0] = s[0] * (1.0f / 512.0f);
}

extern "C" void kernel_launch(void* const* d_in, const int* in_sizes, int n_in,
                              void* d_out, int out_size, void* d_ws, size_t ws_size,
                              hipStream_t stream) {
  const float* outputs = (const float*)d_in[0];
  const float* Wemb    = (const float*)d_in[1];
  const float* bemb    = (const float*)d_in[2];
  const float* Wi      = (const float*)d_in[3];
  const float* Wh      = (const float*)d_in[4];
  const float* lb      = (const float*)d_in[5];
  const float* W1      = (const float*)d_in[6];
  const float* W2      = (const float*)d_in[7];
  const float* av      = (const float*)d_in[8];
  // d_in[9] = N (known constant 512)

  float* ws   = (float*)d_ws;
  float* coef = ws;                        // 1920 floats
  float* WhT  = coef + 2048;               // 512*128
  float* W2T  = WhT + (size_t)512 * 128;   // 128*128
  float* maxd = W2T + (size_t)128 * 128;   // 512

  hipLaunchKernelGGL(coef_k, dim3(1), dim3(512), 0, stream,
                     Wemb, bemb, Wi, W1, lb, coef);
  hipLaunchKernelGGL(transpose_k, dim3(640), dim3(128), 0, stream, Wh, W2, WhT, W2T);
  hipLaunchKernelGGL(decode_k, dim3(NBLK), dim3(1024), 0, stream,
                     outputs, WhT, Wh, W2T, av, coef, maxd);
  hipLaunchKernelGGL(reduce_k, dim3(1), dim3(512), 0, stream, maxd, (float*)d_out);
}